// Round 7
// baseline (24446.733 us; speedup 1.0000x reference)
//
#include <hip/hip_runtime.h>
#include <hip/hip_bf16.h>
#include <math.h>

typedef __hip_bfloat16 bf16;

__device__ __forceinline__ float b2f(bf16 x){ return __bfloat162float(x); }
__device__ __forceinline__ bf16  f2b(float x){ return __float2bfloat16(x); }

#define NUSERS   10000
#define NPOIS    50000
#define SEQL     100
#define NNODES   60001
#define BATCH    1024
#define NNZG     1920000
#define NNZH     1600000
#define BL       (BATCH*SEQL)          // 102400
#define BLD      (BL*128)              // 13,107,200 elems
#define NND      (NNODES*128)          // 7,680,128
#define CN       (60000*128)           // 7,680,000
#define PD       (NPOIS*128)           // 6,400,000

__device__ __forceinline__ void  stc(bf16* p,  float v){ *p = f2b(v); }
__device__ __forceinline__ void  stc(float* p, float v){ *p = v; }
__device__ __forceinline__ float ldc(const bf16* p){ return b2f(*p); }
__device__ __forceinline__ float ldc(const float* p){ return *p; }

// Safe float atomic add via integer CAS (works on any memory type).
__device__ __forceinline__ void atomAddF(float* p, float v){
    unsigned int* u = (unsigned int*)p;
    unsigned int old = __hip_atomic_load(u, __ATOMIC_RELAXED, __HIP_MEMORY_SCOPE_AGENT);
    while (true){
        unsigned int assumed = old;
        float f = __uint_as_float(assumed) + v;
        old = atomicCAS(u, assumed, __float_as_uint(f));
        if (old == assumed) break;
    }
}

// ---------- zero-fill ----------
__global__ __launch_bounds__(256) void k_zero(float* __restrict__ p, int n4){
    int i = blockIdx.x*256 + threadIdx.x;
    if (i < n4) ((float4*)p)[i] = make_float4(0.f,0.f,0.f,0.f);
}

// ---------- init: nodes(bf16)=src, acc(f32)=src ----------
__global__ __launch_bounds__(256) void k_init(bf16* __restrict__ nodes, float* __restrict__ acc,
                                              const float* __restrict__ src, int n){
    int i = blockIdx.x*256 + threadIdx.x;
    if (i >= n) return;
    float v = src[i];
    nodes[i] = f2b(v); acc[i] = v;
}

// ---------- row gather bf16 table -> bf16 dst ----------
__global__ __launch_bounds__(256) void k_gather_b(bf16* __restrict__ dst,
                                                  const bf16* __restrict__ table,
                                                  const int* __restrict__ idx, int rows){
    int gid = blockIdx.x*256 + threadIdx.x;
    if (gid >= rows*128) return;
    int r = gid >> 7, c = gid & 127;
    dst[(size_t)r*128 + c] = table[(size_t)idx[r]*128 + c];
}

// ---------- row gather f32 table -> f32 dst ----------
__global__ __launch_bounds__(256) void k_gather_f(float* __restrict__ dst,
                                                  const float* __restrict__ table,
                                                  const int* __restrict__ idx, int rows){
    int gid = blockIdx.x*256 + threadIdx.x;
    if (gid >= rows*128) return;
    int r = gid >> 7, c = gid & 127;
    dst[(size_t)r*128 + c] = table[(size_t)idx[r]*128 + c];
}

// ---------- geo einsum: geo[b,l,c] = sum_s adj[b,l,s]*seq[b,s,c] ----------
__global__ __launch_bounds__(256) void k_geo(bf16* __restrict__ geo,
                                             const bf16* __restrict__ seq,
                                             const float* __restrict__ adj){
    __shared__ float sq[SEQL*128];
    int b = blockIdx.x, tid = threadIdx.x;
    const bf16* src = seq + (size_t)b*SEQL*128;
    for (int i = tid; i < SEQL*128; i += 256) sq[i] = b2f(src[i]);
    __syncthreads();
    const float* ab = adj + (size_t)b*SEQL*SEQL;
    for (int o = tid; o < SEQL*128; o += 256){
        int l = o >> 7, c = o & 127;
        const float* arow = ab + l*SEQL;
        float sum = 0.f;
        for (int s = 0; s < SEQL; s++) sum += arow[s] * sq[s*128 + c];
        geo[(size_t)b*SEQL*128 + o] = f2b(sum);
    }
}

// ---------- tot = seq + geo + pos_local[l+1] ----------
__global__ __launch_bounds__(256) void k_tot(bf16* __restrict__ tot,
                                             const bf16* __restrict__ seq,
                                             const bf16* __restrict__ geo,
                                             const float* __restrict__ posl, int n){
    int i = blockIdx.x*256 + threadIdx.x;
    if (i >= n) return;
    int c = i & 127, bl = i >> 7, l = bl % SEQL;
    tot[i] = f2b(b2f(seq[i]) + b2f(geo[i]) + posl[(l+1)*128 + c]);
}

// ---------- naive in-place-safe GEMM ----------
template<typename TA, typename TC>
__global__ __launch_bounds__(256) void k_ngemm(const TA* __restrict__ A,
                                               const float* __restrict__ W, int wstride, int woff,
                                               const float* __restrict__ bias, int boff,
                                               TC* __restrict__ C, int act){
    __shared__ float Al[8*130];
    __shared__ float Wl[64*130];
    int tid = threadIdx.x;
    int m0 = blockIdx.x * 8;
    #pragma unroll
    for (int i = 0; i < 4; i++){
        int idx = tid + i*256;            // [0,1024)
        int r = idx >> 7, k = idx & 127;
        Al[r*130 + k] = ldc(&A[(size_t)(m0+r)*128 + k]);
    }
    int n = tid & 127, rb = tid >> 7;     // rb in {0,1}
    float acc[4] = {0.f,0.f,0.f,0.f};
    for (int kp = 0; kp < 128; kp += 64){
        __syncthreads();
        #pragma unroll
        for (int i = 0; i < 32; i++){
            int idx = tid + i*256;        // [0,8192)
            int nn = idx >> 6, kk = idx & 63;
            Wl[kk*130 + nn] = W[(size_t)nn*wstride + woff + kp + kk];
        }
        __syncthreads();
        #pragma unroll
        for (int rr = 0; rr < 4; rr++){
            int r = rb + rr*2;
            float s = 0.f;
            for (int kk = 0; kk < 64; kk++)
                s += Al[r*130 + kp + kk] * Wl[kk*130 + n];
            acc[rr] += s;
        }
    }
    #pragma unroll
    for (int rr = 0; rr < 4; rr++){
        int m = m0 + rb + rr*2;
        float v = acc[rr];
        if (bias) v += bias[boff + n];
        if (act == 1) v = fmaxf(v, 0.f);
        stc(&C[(size_t)m*128 + n], v);
    }
}

// ---------- per-(b,h) attention: softmax(QK^T/4)V; O may alias Q's plane ----------
__global__ __launch_bounds__(256) void k_attn(bf16* __restrict__ o,
                                              const bf16* __restrict__ Qq,
                                              const bf16* __restrict__ Qk,
                                              const bf16* __restrict__ Qv){
    __shared__ float q[SEQL*17], k[SEQL*17], v[SEQL*17], s[SEQL*101];
    int b = blockIdx.x >> 3, h = blockIdx.x & 7, tid = threadIdx.x;
    size_t base = (size_t)b*SEQL*128 + h*16;
    for (int t = tid; t < SEQL*16; t += 256){
        int l = t >> 4, j = t & 15;
        size_t off = base + (size_t)l*128 + j;
        q[l*17+j] = b2f(Qq[off]);
        k[l*17+j] = b2f(Qk[off]);
        v[l*17+j] = b2f(Qv[off]);
    }
    __syncthreads();
    for (int t = tid; t < SEQL*SEQL; t += 256){
        int i = t / SEQL, j = t % SEQL;
        float sum = 0.f;
        #pragma unroll
        for (int u = 0; u < 16; u++) sum += q[i*17+u]*k[j*17+u];
        s[i*101+j] = sum * 0.25f;
    }
    __syncthreads();
    if (tid < SEQL){
        float m = -1e30f;
        for (int j=0;j<SEQL;j++) m = fmaxf(m, s[tid*101+j]);
        float sum = 0.f;
        for (int j=0;j<SEQL;j++){ float e = __expf(s[tid*101+j]-m); s[tid*101+j]=e; sum+=e; }
        float inv = 1.f/sum;
        for (int j=0;j<SEQL;j++) s[tid*101+j] *= inv;
    }
    __syncthreads();
    for (int t = tid; t < SEQL*16; t += 256){
        int i = t >> 4, u = t & 15;
        float sum = 0.f;
        for (int j = 0; j < SEQL; j++) sum += s[i*101+j]*v[j*17+u];
        o[base + (size_t)i*128 + u] = f2b(sum);
    }
}

// ---------- users = mean_l(o2) -> nodes[uidx[b]] ----------
__global__ __launch_bounds__(128) void k_mean_users(bf16* __restrict__ nodes,
                                                    const bf16* __restrict__ o,
                                                    const int* __restrict__ uidx){
    int b = blockIdx.x, c = threadIdx.x;
    const bf16* p = o + (size_t)b*SEQL*128 + c;
    float sum = 0.f;
    for (int l = 0; l < SEQL; l++) sum += b2f(p[l*128]);
    nodes[(size_t)uidx[b]*128 + c] = f2b(sum * (1.f/(float)SEQL));
}

// ---------- atomic SpMM: y[rows[e]] += vals[e]*x[cols[e]] ----------
__global__ __launch_bounds__(256) void k_spmm(float* __restrict__ y,
                                              const int* __restrict__ rows,
                                              const int* __restrict__ cols,
                                              const float* __restrict__ vals,
                                              const bf16* __restrict__ x, int nnz){
    int gid = blockIdx.x*256 + threadIdx.x;
    if (gid >= nnz*32) return;
    int e = gid >> 5, qd = gid & 31;
    int r = rows[e], cl = cols[e];
    float val = vals[e];
    const bf16* xp = x + (size_t)cl*128 + qd*4;
    float x0 = b2f(xp[0]), x1 = b2f(xp[1]), x2 = b2f(xp[2]), x3 = b2f(xp[3]);
    float* yp = y + (size_t)r*128 + qd*4;
    atomAddF(yp+0, val*x0);
    atomAddF(yp+1, val*x1);
    atomAddF(yp+2, val*x2);
    atomAddF(yp+3, val*x3);
}

// ---------- nodes(bf16)[:60000] = Cbuf; acc(f32) += Cbuf ----------
__global__ __launch_bounds__(256) void k_commit(bf16* __restrict__ nodes, float* __restrict__ acc,
                                                const float* __restrict__ Cb, int n){
    int i = blockIdx.x*256 + threadIdx.x;
    if (i >= n) return;
    float v = Cb[i];
    nodes[i] = f2b(v);
    acc[i] += v;
}

__global__ __launch_bounds__(256) void k_scale(float* __restrict__ a, int n){
    int i = blockIdx.x*256 + threadIdx.x;
    if (i < n) a[i] *= (1.f/3.f);
}

// ---------- global branch init ----------
__global__ __launch_bounds__(256) void k_initg(bf16* __restrict__ xg, float* __restrict__ accg,
                                               const float* __restrict__ ne, int n){
    int i = blockIdx.x*256 + threadIdx.x;
    if (i >= n) return;
    float v = ne[(size_t)NUSERS*128 + i];
    xg[i] = f2b(v); accg[i] = v;
}

__global__ __launch_bounds__(256) void k_commit2(bf16* __restrict__ xg, float* __restrict__ accg,
                                                 const float* __restrict__ tmp, int n){
    int i = blockIdx.x*256 + threadIdx.x;
    if (i >= n) return;
    float v = tmp[i];
    xg[i] = f2b(v);
    accg[i] += v;
}

// ---------- fusion: acc_poi += accg/3; emit pois output (f32!) ----------
__global__ __launch_bounds__(256) void k_fusion(float* __restrict__ accP,
                                                const float* __restrict__ accg,
                                                float* __restrict__ outp, int n){
    int i = blockIdx.x*256 + threadIdx.x;
    if (i >= n) return;
    float v = accP[i] + accg[i]*(1.f/3.f);
    accP[i] = v;
    outp[i] = v;
}

// ================= HEAD (all f32, simple per-row kernels) =================

__global__ __launch_bounds__(128) void k_hs(float* __restrict__ hs, const float* __restrict__ sh,
                                            const float* __restrict__ lens){
    int b = blockIdx.x, c = threadIdx.x;
    const float* p = sh + (size_t)b*SEQL*128 + c;
    float sum = 0.f;
    for (int l = 0; l < SEQL; l++) sum += p[l*128];
    hs[b*128 + c] = sum / lens[b];
}

__global__ __launch_bounds__(128) void k_posw(float* __restrict__ posW,
                                              const float* __restrict__ pg,
                                              const float* __restrict__ w1w){
    __shared__ float sm[128];
    int p = blockIdx.x, n = threadIdx.x;
    sm[n] = pg[p*128 + n];
    __syncthreads();
    const float* wr = w1w + (size_t)n*256;
    float s = 0.f;
    for (int k = 0; k < 128; k++) s += sm[k]*wr[k];
    posW[p*128 + n] = s;
}

__global__ __launch_bounds__(128) void k_hproj(float* __restrict__ hp,
                                               const float* __restrict__ hs,
                                               const float* __restrict__ g2w){
    __shared__ float sm[128];
    int b = blockIdx.x, n = threadIdx.x;
    sm[n] = hs[b*128 + n];
    __syncthreads();
    const float* wr = g2w + (size_t)n*128;
    float s = 0.f;
    for (int k = 0; k < 128; k++) s += sm[k]*wr[k];
    hp[b*128 + n] = s;
}

__global__ __launch_bounds__(128) void k_nh1(bf16* __restrict__ nh,
                                             const float* __restrict__ seqh,
                                             const float* __restrict__ w1w,
                                             const float* __restrict__ w1b,
                                             const float* __restrict__ posW,
                                             const int* __restrict__ masks){
    __shared__ float sm[128];
    int m = blockIdx.x, n = threadIdx.x;
    sm[n] = seqh[(size_t)m*128 + n];
    __syncthreads();
    int l = m % SEQL;
    int p = (l+1) * masks[m];
    const float* wr = w1w + (size_t)n*256 + 128;
    float s = 0.f;
    for (int k = 0; k < 128; k++) s += sm[k]*wr[k];
    s += posW[p*128 + n] + w1b[n];
    nh[(size_t)m*128 + n] = f2b(tanhf(s));
}

__global__ __launch_bounds__(128) void k_nh2(bf16* __restrict__ nh,
                                             const float* __restrict__ g1w,
                                             const float* __restrict__ g1b,
                                             const float* __restrict__ hp){
    __shared__ float sm[128];
    int m = blockIdx.x, n = threadIdx.x;
    sm[n] = b2f(nh[(size_t)m*128 + n]);
    __syncthreads();
    int b = m / SEQL;
    const float* wr = g1w + (size_t)n*128;
    float s = 0.f;
    for (int k = 0; k < 128; k++) s += sm[k]*wr[k];
    s += g1b[n] + hp[b*128 + n];
    nh[(size_t)m*128 + n] = f2b(1.f/(1.f+__expf(-s)));
}

__global__ __launch_bounds__(128) void k_beta(float* __restrict__ beta,
                                              const bf16* __restrict__ nh,
                                              const float* __restrict__ w2){
    __shared__ float red[128];
    int m = blockIdx.x, c = threadIdx.x;
    red[c] = b2f(nh[(size_t)m*128 + c]) * w2[c];
    __syncthreads();
    for (int s = 64; s > 0; s >>= 1){
        if (c < s) red[c] += red[c+s];
        __syncthreads();
    }
    if (c == 0) beta[m] = red[0];
}

__global__ __launch_bounds__(128) void k_final(float* __restrict__ out,
                                               const float* __restrict__ beta,
                                               const float* __restrict__ seqh,
                                               const float* __restrict__ acc,
                                               const int* __restrict__ uidx){
    int b = blockIdx.x, c = threadIdx.x;
    const float* sh = seqh + (size_t)b*SEQL*128 + c;
    const float* bp = beta + b*SEQL;
    float sel = 0.f;
    for (int l = 0; l < SEQL; l++) sel += bp[l]*sh[l*128];
    out[b*128 + c] = sel + acc[(size_t)uidx[b]*128 + c];
}

extern "C" void kernel_launch(void* const* d_in, const int* in_sizes, int n_in,
                              void* d_out, int out_size, void* d_ws, size_t ws_size,
                              hipStream_t stream){
    const float* nodes_emb     = (const float*)d_in[0];
    const float* pos_emb_local = (const float*)d_in[1];
    const float* fc_geo_w      = (const float*)d_in[2];
    const float* fc_geo_b      = (const float*)d_in[3];
    const float* in_proj_w     = (const float*)d_in[4];
    const float* in_proj_b     = (const float*)d_in[5];
    const float* out_proj_w    = (const float*)d_in[6];
    const float* out_proj_b    = (const float*)d_in[7];
    const float* pos_emb_glob  = (const float*)d_in[8];
    const float* w1_w          = (const float*)d_in[9];
    const float* w1_b          = (const float*)d_in[10];
    const float* w_2           = (const float*)d_in[11];
    const float* glu1_w        = (const float*)d_in[12];
    const float* glu1_b        = (const float*)d_in[13];
    const float* glu2_w        = (const float*)d_in[14];
    const int*   G_rows        = (const int*)d_in[15];
    const int*   G_cols        = (const int*)d_in[16];
    const float* G_vals        = (const float*)d_in[17];
    const int*   HG_rows       = (const int*)d_in[18];
    const int*   HG_cols       = (const int*)d_in[19];
    const float* HG_vals       = (const float*)d_in[20];
    const int*   seqs          = (const int*)d_in[21];
    const int*   masks         = (const int*)d_in[22];
    const float* adjs          = (const float*)d_in[23];
    const int*   uidx          = (const int*)d_in[24];
    const float* lens          = (const float*)d_in[25];
    const int*   rev_seqs      = (const int*)d_in[26];
    float* out = (float*)d_out;   // OUTPUT IS FLOAT32 (reference returns jnp.float32)

    // ---- workspace layout; max offset used = 124,723,968 B ----
    char* base = (char*)d_ws;
    bf16*  nodes = (bf16*)base;                               // [0, 15,360,256)
    float* acc   = (float*)(base + 15360256);                 // [.., 46,080,768)
    char*  R     = base + 15360256 + 30720512;                // [46,080,768, 124,723,968)
    // layer-phase aliases inside R:
    bf16* P1 = (bf16*)R;          // BLD bf16
    bf16* P2 = P1 + BLD;
    bf16* P3 = P2 + BLD;
    float* Cbuf = (float*)R;      // CN f32 (used only after P1/P2 dead)
    bf16*  xg   = (bf16*)R;                          // PD bf16
    float* gtmp = (float*)(R + 12800000);            // PD f32
    float* accg = (float*)(R + 12800000 + 25600000); // PD f32
    // head-phase aliases:
    float* H1f  = (float*)R;                         // BLD f32
    bf16*  nh   = (bf16*)(R + 52428800);             // BLD bf16
    float* hs    = (float*)base;                     // small bufs in dead nodes region
    float* hproj = (float*)(base + 524288);
    float* posW  = (float*)(base + 1048576);
    float* betaB = (float*)(base + 1100288);

    auto gemm = [&](const bf16* A, const float* W, int wstride, int woff,
                    const float* bias, int boff, bf16* Cp, int act){
        k_ngemm<bf16,bf16><<<dim3(BL/8), dim3(256), 0, stream>>>(
            A, W, wstride, woff, bias, boff, Cp, act);
    };

    // init: nodes (bf16) = nodes_emb, acc (f32) = nodes_emb
    k_init<<<dim3((NND+255)/256), dim3(256), 0, stream>>>(nodes, acc, nodes_emb, NND);

    for (int layer = 0; layer < 2; layer++){
        k_gather_b<<<dim3((BL*128+255)/256), dim3(256), 0, stream>>>(P1, nodes, seqs, BL);
        k_geo<<<dim3(BATCH), dim3(256), 0, stream>>>(P2, P1, adjs);
        gemm(P2, fc_geo_w, 128, 0, fc_geo_b, 0, P2, 1);   // relu, in-place (row-owned)
        k_tot<<<dim3((BLD+255)/256), dim3(256), 0, stream>>>(P3, P1, P2, pos_emb_local, BLD);
        gemm(P3, in_proj_w, 128, 0,       in_proj_b, 0,   P1, 0); // Q
        gemm(P3, in_proj_w, 128, 128*128, in_proj_b, 128, P2, 0); // K
        gemm(P3, in_proj_w, 128, 256*128, in_proj_b, 256, P3, 0); // V in-place
        k_attn<<<dim3(BATCH*8), dim3(256), 0, stream>>>(P1, P1, P2, P3);  // O over Q
        gemm(P1, out_proj_w, 128, 0, out_proj_b, 0, P2, 0);
        k_mean_users<<<dim3(BATCH), dim3(128), 0, stream>>>(nodes, P2, uidx);
        k_zero<<<dim3((CN/4+255)/256), dim3(256), 0, stream>>>(Cbuf, CN/4);
        k_spmm<<<dim3((NNZG*32+255)/256), dim3(256), 0, stream>>>(Cbuf, G_rows, G_cols, G_vals, nodes, NNZG);
        k_commit<<<dim3((CN+255)/256), dim3(256), 0, stream>>>(nodes, acc, Cbuf, CN);
    }
    // local = acc/3
    k_scale<<<dim3((NND+255)/256), dim3(256), 0, stream>>>(acc, NND);

    // global hypergraph branch
    k_initg<<<dim3((PD+255)/256), dim3(256), 0, stream>>>(xg, accg, nodes_emb, PD);
    for (int it = 0; it < 2; it++){
        k_zero<<<dim3((PD/4+255)/256), dim3(256), 0, stream>>>(gtmp, PD/4);
        k_spmm<<<dim3((NNZH*32+255)/256), dim3(256), 0, stream>>>(gtmp, HG_rows, HG_cols, HG_vals, xg, NNZH);
        k_commit2<<<dim3((PD+255)/256), dim3(256), 0, stream>>>(xg, accg, gtmp, PD);
    }
    // fusion: pois rows of acc += accg/3, emit pois output (f32, offset in f32 elems)
    k_fusion<<<dim3((PD+255)/256), dim3(256), 0, stream>>>(acc + (size_t)NUSERS*128, accg, out + BATCH*128, PD);

    // ===== head (f32 path) =====
    k_gather_f<<<dim3((BL*128+255)/256), dim3(256), 0, stream>>>(H1f, acc, rev_seqs, BL);
    k_hs<<<dim3(BATCH), dim3(128), 0, stream>>>(hs, H1f, lens);
    k_hproj<<<dim3(BATCH), dim3(128), 0, stream>>>(hproj, hs, glu2_w);
    k_posw<<<dim3(SEQL+1), dim3(128), 0, stream>>>(posW, pos_emb_glob, w1_w);
    k_nh1<<<dim3(BL), dim3(128), 0, stream>>>(nh, H1f, w1_w, w1_b, posW, masks);
    k_nh2<<<dim3(BL), dim3(128), 0, stream>>>(nh, glu1_w, glu1_b, hproj);
    k_beta<<<dim3(BL), dim3(128), 0, stream>>>(betaB, nh, w_2);
    k_final<<<dim3(BATCH), dim3(128), 0, stream>>>(out, betaB, H1f, acc, uidx);
}